// Round 12
// baseline (381.514 us; speedup 1.0000x reference)
//
#include <hip/hip_runtime.h>
#include <math.h>

#define CIN    128
#define HID    128
#define HDIM   64
#define WDIM   64
#define HW     4096
#define NBATCH 16
#define LROW   136                  // shorts per LDS row (272 B, b128-aligned)
#define WXSZ   (4 * 8 * 64 * 8)    // 16384 shorts per he-slice (x-part frag)
#define WHSZ   (4 * 12 * 64 * 8)   // 24576 shorts per he-slice (h-part frag, ch-grouped)
#define HTWORDS (2 * NBATCH * WDIM * HID)  // 262144 tagged u32

typedef short short8 __attribute__((ext_vector_type(8)));
typedef float f32x4  __attribute__((ext_vector_type(4)));
typedef unsigned int u32x4 __attribute__((ext_vector_type(4)));

// agent scope (sc0+sc1 -> MALL coherence point)
#define ASTOREA(p, v) __hip_atomic_store((p), (v), __ATOMIC_RELAXED, __HIP_MEMORY_SCOPE_AGENT)

__device__ __forceinline__ unsigned short f2bf(float f) {
    union { float f; unsigned int u; } v; v.f = f;
    unsigned int r = v.u + 0x7fffu + ((v.u >> 16) & 1u);   // RNE
    return (unsigned short)(r >> 16);
}
__device__ __forceinline__ float sigm(float x)  { return 1.0f / (1.0f + __expf(-x)); }
__device__ __forceinline__ float tanhft(float x){ return 2.0f / (1.0f + __expf(-2.0f * x)) - 1.0f; }

// issue 9 MALL-coherent loads via 32-bit voffset + uniform SGPR base +
// group-immediate; NO wait (batched, software-pipelined poll issue)
#define LD9_OFF(V, OFF, BASE, IMM)                                             \
    asm volatile(                                                              \
        "global_load_dword %0, %9,  %18 offset:" IMM " sc0 sc1\n\t"            \
        "global_load_dword %1, %10, %18 offset:" IMM " sc0 sc1\n\t"            \
        "global_load_dword %2, %11, %18 offset:" IMM " sc0 sc1\n\t"            \
        "global_load_dword %3, %12, %18 offset:" IMM " sc0 sc1\n\t"            \
        "global_load_dword %4, %13, %18 offset:" IMM " sc0 sc1\n\t"            \
        "global_load_dword %5, %14, %18 offset:" IMM " sc0 sc1\n\t"            \
        "global_load_dword %6, %15, %18 offset:" IMM " sc0 sc1\n\t"            \
        "global_load_dword %7, %16, %18 offset:" IMM " sc0 sc1\n\t"            \
        "global_load_dword %8, %17, %18 offset:" IMM " sc0 sc1"                \
        : "=&v"((V)[0]), "=&v"((V)[1]), "=&v"((V)[2]), "=&v"((V)[3]),          \
          "=&v"((V)[4]), "=&v"((V)[5]), "=&v"((V)[6]), "=&v"((V)[7]),          \
          "=&v"((V)[8])                                                        \
        : "v"((OFF)[0]), "v"((OFF)[1]), "v"((OFF)[2]), "v"((OFF)[3]),          \
          "v"((OFF)[4]), "v"((OFF)[5]), "v"((OFF)[6]), "v"((OFF)[7]),          \
          "v"((OFF)[8]), "s"(BASE)                                             \
        : "memory")

// consume point: wait all outstanding vmem; ties the 9 regs so uses come after
__device__ __forceinline__ void wait9(unsigned v[9]) {
    asm volatile("s_waitcnt vmcnt(0)"
        : "+v"(v[0]), "+v"(v[1]), "+v"(v[2]), "+v"(v[3]), "+v"(v[4]),
          "+v"(v[5]), "+v"(v[6]), "+v"(v[7]), "+v"(v[8]) :: "memory");
}

// ---------------------------------------------------------------------------
// Pack: Wx / Wh fragment order (Wh ch-grouped: ks = grp*3 + t), bias fold,
// zero the tag buffer (replay/graph safe).
// ---------------------------------------------------------------------------
__global__ void pack_kernel(const float* __restrict__ W_is,
                            const float* __restrict__ b_is,
                            const float* __restrict__ W_ss,
                            const float* __restrict__ b_ss,
                            unsigned short* __restrict__ Wx,
                            unsigned short* __restrict__ Wh,
                            float* __restrict__ bias_p,
                            unsigned int* __restrict__ ht) {
    int idx = blockIdx.x * blockDim.x + threadIdx.x;
    if (idx < 131072) {                 // 8 he * WXSZ
        int j = idx & 7, lane = (idx >> 3) & 63, rest = idx >> 9;
        int ks = rest & 7, gg = rest >> 3, gate = gg & 3, he = gg >> 2;
        int n = gate * 128 + he * 16 + (lane & 15);
        int k = ks * 32 + ((lane >> 4) * 8) + j;        // k = t*128 + c
        Wx[idx] = f2bf(W_is[((size_t)n * CIN + (k & 127)) * 3 + (k >> 7)]);
    }
    if (idx < 196608) {                 // 8 he * WHSZ
        int j = idx & 7, lane = (idx >> 3) & 63, rest = idx >> 9;   // rest < 384
        int ks = rest % 12, gg = rest / 12, gate = gg & 3, he = gg >> 2;
        int grp = ks / 3, t = ks - 3 * grp;
        int c = grp * 32 + ((lane >> 4) * 8) + j;
        int n = gate * 128 + he * 16 + (lane & 15);
        Wh[idx] = f2bf(W_ss[((size_t)n * HID + c) * 3 + t]);
    }
    if (idx < 512) bias_p[idx] = b_is[idx] + b_ss[idx];
    if (idx < HTWORDS) ht[idx] = 0u;
}

// ---------------------------------------------------------------------------
// xt: x [b][c][r][w] f32 -> xT [b][r][w][c] bf16 (coalesced both sides)
// ---------------------------------------------------------------------------
__global__ __launch_bounds__(256) void xt_kernel(const float* __restrict__ x,
                                                 unsigned int* __restrict__ xT32) {
    __shared__ unsigned short t[128 * 66];
    const int tid = threadIdx.x;
    const int b = blockIdx.x >> 6;
    const int r = blockIdx.x & 63;
#pragma unroll
    for (int i = 0; i < 32; ++i) {
        int flat = i * 256 + tid;
        int c = flat >> 6, w = flat & 63;
        t[c * 66 + w] = f2bf(x[(((size_t)b * 128 + c) * 64 + r) * 64 + w]);
    }
    __syncthreads();
    unsigned* o = xT32 + ((size_t)(b * 64 + r) * 64) * 64;
#pragma unroll
    for (int i = 0; i < 16; ++i) {
        int flat = i * 256 + tid;
        int w = flat >> 6, cp = flat & 63;
        o[w * 64 + cp] = (unsigned)t[(2 * cp) * 66 + w]
                       | ((unsigned)t[(2 * cp + 1) * 66 + w] << 16);
    }
}

// ---------------------------------------------------------------------------
// Persistent LSTM: grid 128 = (b, he), 1 blk/CU, wave-autonomous, tagged
// agent-scope h words (bf16<<16 | r+1), parity ping-pong.
// v12: ALL 36 poll loads (4 ch-groups x 9 words) issued together at row top
// — one MALL RT, hidden under x-prefetch + GEMM_X — then a single combined
// check. (R11 staggered G1-3 issue after each consume, exposing ~550cy x3
// per row since 250cy of stage+MFMA can't hide an 800cy RT; the groups all
// become ready simultaneously anyway — every producer publishes its 4 words
// in one epilogue.) On pass: 36 LDS stages + 48 MFMA with no further waits.
// Loads use 32-bit voffset + SGPR base + offset:g*128 immediate (channel
// groups are 128 B apart) to keep VGPR pressure low.
// ---------------------------------------------------------------------------
__global__ __launch_bounds__(256, 1) void lstm_kernel(
        const unsigned int* __restrict__ xT32,
        const unsigned short* __restrict__ Wx,
        const unsigned short* __restrict__ Wh,
        const float* __restrict__ bias_p,
        unsigned int* ht,
        float* __restrict__ out) {
    __shared__ __align__(16) unsigned short lds_bx[WXSZ];           // 32 KiB
    __shared__ __align__(16) unsigned short lds_bh[WHSZ];           // 48 KiB
    __shared__ __align__(16) unsigned short ldsx[4][2][17 * LROW];  // 36.1 KiB
    __shared__ __align__(16) unsigned short ldsh[4][18 * LROW];     // 19.1 KiB

    const int tid  = threadIdx.x;
    const int b    = blockIdx.x & 15;
    const int he   = blockIdx.x >> 4;
    const int wv   = tid >> 6;
    const int lane = tid & 63;
    const int quad = lane >> 4;
    const int l15  = lane & 15;

    // ---- prologue: weight slices -> LDS (block-coop, once) ----
    {
        const u32x4* src = (const u32x4*)(Wx + (size_t)he * WXSZ);
        u32x4* dst = (u32x4*)lds_bx;
#pragma unroll
        for (int p = 0; p < 8; ++p) dst[p * 256 + tid] = src[p * 256 + tid];
        const u32x4* srh = (const u32x4*)(Wh + (size_t)he * WHSZ);
        u32x4* dsh = (u32x4*)lds_bh;
#pragma unroll
        for (int p = 0; p < 12; ++p) dsh[p * 256 + tid] = srh[p * 256 + tid];
    }

    // per-lane poll geometry: word i covers (row_i, ch32_i); rows clamped,
    // halo rows masked (tag substituted with `want`, data -> bf16 0)
    unsigned boff[9];   // byte offset (rc*128 + ch32)*4; group adds offset:g*128
    unsigned okm[9];
#pragma unroll
    for (int i = 0; i < 9; ++i) {
        int wi = i * 64 + lane;
        int row_i = wi >> 5, ch32 = wi & 31;
        int rr = wv * 16 - 1 + row_i;
        int rc = rr < 0 ? 0 : (rr > 63 ? 63 : rr);
        boff[i] = (unsigned)((rc * 128 + ch32) * 4);
        okm[i]  = ((unsigned)rr < 64u) ? 0xffffffffu : 0u;
    }

#define HCHECK(HV, WANT, DIFF)                                                 \
    {                                                                          \
        (DIFF) = 0u;                                                           \
        _Pragma("unroll")                                                      \
        for (int i = 0; i < 9; ++i) {                                          \
            (HV)[i] = ((HV)[i] & okm[i]) | ((WANT) & ~okm[i]);                 \
            (DIFF) |= ((HV)[i] ^ (WANT)) & 0xffffu;                            \
        }                                                                      \
    }

#define HSTAGE(HV, GRP, HP)                                                    \
    _Pragma("unroll")                                                          \
    for (int i = 0; i < 9; ++i) {                                              \
        int wi = i * 64 + lane;                                                \
        (HP)[(wi >> 5) * LROW + (GRP) * 32 + (wi & 31)] =                      \
            (unsigned short)((HV)[i] >> 16);                                   \
    }

#define HGEMM(GRP, HP)                                                         \
    _Pragma("unroll")                                                          \
    for (int t = 0; t < 3; ++t) {                                              \
        const int ks = (GRP) * 3 + t;                                          \
        short8 a = *(const short8*)&(HP)[(l15 + t) * LROW + (GRP) * 32 + quad * 8]; \
        _Pragma("unroll")                                                      \
        for (int g = 0; g < 4; ++g) {                                          \
            short8 bq = *(const short8*)&lds_bh[((g * 12 + ks) * 64 + lane) * 8]; \
            acc[g] = __builtin_amdgcn_mfma_f32_16x16x32_bf16(a, bq, acc[g], 0, 0, 0); \
        }                                                                      \
    }

#define GEMM_XW(XP)                                                            \
    _Pragma("unroll")                                                          \
    for (int ks = 0; ks < 8; ++ks) {                                           \
        const int t = ks >> 2, c0 = (ks & 3) * 32;                             \
        short8 a = *(const short8*)&(XP)[(l15 + t) * LROW + c0 + quad * 8];    \
        _Pragma("unroll")                                                      \
        for (int g = 0; g < 4; ++g) {                                          \
            short8 bq = *(const short8*)&lds_bx[((g * 8 + ks) * 64 + lane) * 8]; \
            acc[g] = __builtin_amdgcn_mfma_f32_16x16x32_bf16(a, bq, acc[g], 0, 0, 0); \
        }                                                                      \
    }

#define ISSUE36(HS)                                                            \
    {                                                                          \
        LD9_OFF(hv0, boff, (HS), "0");                                         \
        LD9_OFF(hv1, boff, (HS), "128");                                       \
        LD9_OFF(hv2, boff, (HS), "256");                                       \
        LD9_OFF(hv3, boff, (HS), "384");                                       \
    }

#define CHECK36(WANT, ANY)                                                     \
    {                                                                          \
        unsigned d0_, d1_, d2_, d3_;                                           \
        wait9(hv0); HCHECK(hv0, (WANT), d0_);                                  \
        wait9(hv1); HCHECK(hv1, (WANT), d1_);                                  \
        wait9(hv2); HCHECK(hv2, (WANT), d2_);                                  \
        wait9(hv3); HCHECK(hv3, (WANT), d3_);                                  \
        (ANY) = __ballot((d0_ | d1_ | d2_ | d3_) != 0u);                       \
    }

    // initial x stage (row 0) straight to LDS
    {
        const unsigned* xs = xT32 + ((size_t)(b * 64 + 0) * 64) * 64;
#pragma unroll
        for (int i = 0; i < 17; ++i) {
            int rr = wv * 16 - 1 + i;
            ((unsigned*)ldsx[wv][0])[i * 68 + lane] = (rr >= 0) ? xs[rr * 64 + lane] : 0u;
        }
    }
    __syncthreads();                     // weights + x0 ready (only barrier)
    __builtin_amdgcn_s_setprio(1);

    const int hch = he * 16 + l15;
    const float bi  = bias_p[      hch];
    const float bf_ = bias_p[128 + hch];
    const float bo  = bias_p[256 + hch];
    const float bg  = bias_p[384 + hch];

    f32x4 creg = (f32x4){0.f, 0.f, 0.f, 0.f};

    for (int r = 0; r < HDIM; ++r) {
        const unsigned want = (unsigned)r;
        const unsigned* hs = ht + ((size_t)((r - 1) & 1) * NBATCH + b) * (WDIM * HID);
        unsigned short* hp = ldsh[wv];

        unsigned hv0[9], hv1[9], hv2[9], hv3[9];
        if (r > 0) ISSUE36(hs);            // all 4 groups: one RT, hidden below

        // x prefetch for r+1 into registers (ds_write deferred to row end)
        unsigned xr[17];
        if (r < HDIM - 1) {
            const unsigned* xs = xT32 + ((size_t)(b * 64 + r + 1) * 64) * 64;
#pragma unroll
            for (int i = 0; i < 17; ++i) {
                int rr = wv * 16 - 1 + i;
                xr[i] = (rr >= 0) ? xs[rr * 64 + lane] : 0u;
            }
        }

        f32x4 acc[4];
#pragma unroll
        for (int g = 0; g < 4; ++g) acc[g] = (f32x4){0.f, 0.f, 0.f, 0.f};

        GEMM_XW(ldsx[wv][r & 1]);                          // x-part of row r

        if (r > 0) {
            unsigned long long any;
            CHECK36(want, any);
            if (any != 0ull) {
                __builtin_amdgcn_s_setprio(0);
                do { ISSUE36(hs); CHECK36(want, any); } while (any != 0ull);
                __builtin_amdgcn_s_setprio(1);
            }
            HSTAGE(hv0, 0, hp); HSTAGE(hv1, 1, hp);
            HSTAGE(hv2, 2, hp); HSTAGE(hv3, 3, hp);
            HGEMM(0, hp); HGEMM(1, hp); HGEMM(2, hp); HGEMM(3, hp);
        }

        // ---- epilogue: gates lane-local; publish each h word ASAP ----
        {
            const int w0 = wv * 16 + quad * 4;
            unsigned* hb = ht + ((size_t)(r & 1) * NBATCH + b) * (WDIM * HID);
            f32x4 hv;
#pragma unroll
            for (int e = 0; e < 4; ++e) {
                float zi = acc[0][e] + bi;
                float zf = acc[1][e] + bf_;
                float zo = acc[2][e] + bo;
                float zg = acc[3][e] + bg;
                float ig = sigm(zi), fg = sigm(zf), og = sigm(zo);
                float gg = tanhft(zg);
                float cn = fg * creg[e] + ig * gg;
                creg[e] = cn;
                hv[e]   = og * tanhft(cn);
                ASTOREA(&hb[(w0 + e) * 128 + hch],
                        ((unsigned)f2bf(hv[e]) << 16) | (unsigned)(r + 1));
            }
            *(f32x4*)&out[(((size_t)b * HID + hch) * HDIM + r) * WDIM + w0] = hv;
        }

        // deferred x ds_write for row r+1 (off the inter-block critical path)
        if (r < HDIM - 1) {
            unsigned* xp = (unsigned*)ldsx[wv][(r + 1) & 1];
#pragma unroll
            for (int i = 0; i < 17; ++i) xp[i * 68 + lane] = xr[i];
        }
    }
}

extern "C" void kernel_launch(void* const* d_in, const int* in_sizes, int n_in,
                              void* d_out, int out_size, void* d_ws, size_t ws_size,
                              hipStream_t stream) {
    const float* x    = (const float*)d_in[0];
    const float* W_is = (const float*)d_in[1];
    const float* b_is = (const float*)d_in[2];
    const float* W_ss = (const float*)d_in[3];
    const float* b_ss = (const float*)d_in[4];
    float* out = (float*)d_out;

    // ws: xT bf16[16][64][64][128] | ht u32 | Wx | Wh | bias
    const size_t XT_BYTES = (size_t)16 * 64 * 64 * 128 * 2;   // 16777216
    const size_t HT_BYTES = (size_t)HTWORDS * 4;              //  1048576
    const size_t WX_BYTES = 8 * WXSZ * 2;                     //   262144
    const size_t WH_BYTES = 8 * WHSZ * 2;                     //   393216

    unsigned int*   xT32   = (unsigned int*)d_ws;
    unsigned int*   ht     = (unsigned int*)((char*)d_ws + XT_BYTES);
    unsigned short* Wx     = (unsigned short*)((char*)d_ws + XT_BYTES + HT_BYTES);
    unsigned short* Wh     = (unsigned short*)((char*)d_ws + XT_BYTES + HT_BYTES + WX_BYTES);
    float*          bias_p = (float*)((char*)d_ws + XT_BYTES + HT_BYTES + WX_BYTES + WH_BYTES);

    pack_kernel<<<1024, 256, 0, stream>>>(W_is, b_is, W_ss, b_ss, Wx, Wh, bias_p, ht);
    xt_kernel<<<1024, 256, 0, stream>>>(x, xT32);
    lstm_kernel<<<128, 256, 0, stream>>>(xT32, Wx, Wh, bias_p, ht, out);
}

// Round 16
// 332.026 us; speedup vs baseline: 1.1490x; 1.1490x over previous
//
#include <hip/hip_runtime.h>
#include <math.h>

#define CIN    128
#define HID    128
#define HDIM   64
#define WDIM   64
#define HW     4096
#define NBATCH 16
#define LROW   136                  // shorts per LDS row (272 B, b128-aligned)
#define WXSZ   (4 * 8 * 64 * 8)    // 16384 shorts per he-slice (x-part frag)
#define WHSZ   (4 * 12 * 64 * 8)   // 24576 shorts per he-slice (h-part frag, ch-grouped)
#define HTWORDS (2 * NBATCH * WDIM * HID)  // 262144 tagged u32

typedef short short8 __attribute__((ext_vector_type(8)));
typedef float f32x4  __attribute__((ext_vector_type(4)));
typedef unsigned int u32x4 __attribute__((ext_vector_type(4)));

// agent scope (sc0+sc1 -> MALL coherence point)
#define ASTOREA(p, v) __hip_atomic_store((p), (v), __ATOMIC_RELAXED, __HIP_MEMORY_SCOPE_AGENT)

__device__ __forceinline__ unsigned short f2bf(float f) {
    union { float f; unsigned int u; } v; v.f = f;
    unsigned int r = v.u + 0x7fffu + ((v.u >> 16) & 1u);   // RNE
    return (unsigned short)(r >> 16);
}
__device__ __forceinline__ float sigm(float x)  { return 1.0f / (1.0f + __expf(-x)); }
__device__ __forceinline__ float tanhft(float x){ return 2.0f / (1.0f + __expf(-2.0f * x)) - 1.0f; }

// issue 9 MALL-coherent loads, NO wait (software-pipelined poll issue)
__device__ __forceinline__ void ld9_issue(unsigned v[9], const unsigned* const p[9]) {
    asm volatile(
        "global_load_dword %0, %9,  off sc0 sc1\n\t"
        "global_load_dword %1, %10, off sc0 sc1\n\t"
        "global_load_dword %2, %11, off sc0 sc1\n\t"
        "global_load_dword %3, %12, off sc0 sc1\n\t"
        "global_load_dword %4, %13, off sc0 sc1\n\t"
        "global_load_dword %5, %14, off sc0 sc1\n\t"
        "global_load_dword %6, %15, off sc0 sc1\n\t"
        "global_load_dword %7, %16, off sc0 sc1\n\t"
        "global_load_dword %8, %17, off sc0 sc1"
        : "=&v"(v[0]), "=&v"(v[1]), "=&v"(v[2]), "=&v"(v[3]), "=&v"(v[4]),
          "=&v"(v[5]), "=&v"(v[6]), "=&v"(v[7]), "=&v"(v[8])
        : "v"(p[0]), "v"(p[1]), "v"(p[2]), "v"(p[3]), "v"(p[4]),
          "v"(p[5]), "v"(p[6]), "v"(p[7]), "v"(p[8])
        : "memory");
}
// consume point: wait all outstanding vmem; ties the 9 regs so uses come after
__device__ __forceinline__ void wait9(unsigned v[9]) {
    asm volatile("s_waitcnt vmcnt(0)"
        : "+v"(v[0]), "+v"(v[1]), "+v"(v[2]), "+v"(v[3]), "+v"(v[4]),
          "+v"(v[5]), "+v"(v[6]), "+v"(v[7]), "+v"(v[8]) :: "memory");
}

// ---------------------------------------------------------------------------
// prep: (merged pack + xt, one dispatch). Blocks 0..1023 pack Wx/Wh in
// fragment order (Wh ch-grouped: ks = grp*3 + t), fold bias, zero tags.
// Blocks 1024..2047 transpose x [b][c][r][w] f32 -> xT [b][r][w][c] bf16.
// Branch is block-uniform; __syncthreads only in the xt branch (legal).
// ---------------------------------------------------------------------------
__global__ __launch_bounds__(256) void prep_kernel(
        const float* __restrict__ W_is,
        const float* __restrict__ b_is,
        const float* __restrict__ W_ss,
        const float* __restrict__ b_ss,
        const float* __restrict__ x,
        unsigned short* __restrict__ Wx,
        unsigned short* __restrict__ Wh,
        float* __restrict__ bias_p,
        unsigned int* __restrict__ ht,
        unsigned int* __restrict__ xT32) {
    __shared__ unsigned short t[128 * 66];
    const int tid = threadIdx.x;
    if (blockIdx.x < 1024) {
        int idx = blockIdx.x * 256 + tid;
        if (idx < 131072) {             // 8 he * WXSZ
            int j = idx & 7, lane = (idx >> 3) & 63, rest = idx >> 9;
            int ks = rest & 7, gg = rest >> 3, gate = gg & 3, he = gg >> 2;
            int n = gate * 128 + he * 16 + (lane & 15);
            int k = ks * 32 + ((lane >> 4) * 8) + j;    // k = t*128 + c
            Wx[idx] = f2bf(W_is[((size_t)n * CIN + (k & 127)) * 3 + (k >> 7)]);
        }
        if (idx < 196608) {             // 8 he * WHSZ
            int j = idx & 7, lane = (idx >> 3) & 63, rest = idx >> 9;
            int ks = rest % 12, gg = rest / 12, gate = gg & 3, he = gg >> 2;
            int grp = ks / 3, tt = ks - 3 * grp;
            int c = grp * 32 + ((lane >> 4) * 8) + j;
            int n = gate * 128 + he * 16 + (lane & 15);
            Wh[idx] = f2bf(W_ss[((size_t)n * HID + c) * 3 + tt]);
        }
        if (idx < 512) bias_p[idx] = b_is[idx] + b_ss[idx];
        if (idx < HTWORDS) ht[idx] = 0u;
    } else {
        const int bid = blockIdx.x - 1024;
        const int b = bid >> 6;
        const int r = bid & 63;
#pragma unroll
        for (int i = 0; i < 32; ++i) {
            int flat = i * 256 + tid;
            int c = flat >> 6, w = flat & 63;
            t[c * 66 + w] = f2bf(x[(((size_t)b * 128 + c) * 64 + r) * 64 + w]);
        }
        __syncthreads();
        unsigned* o = xT32 + ((size_t)(b * 64 + r) * 64) * 64;
#pragma unroll
        for (int i = 0; i < 16; ++i) {
            int flat = i * 256 + tid;
            int w = flat >> 6, cp = flat & 63;
            o[w * 64 + cp] = (unsigned)t[(2 * cp) * 66 + w]
                           | ((unsigned)t[(2 * cp + 1) * 66 + w] << 16);
        }
    }
}

// ---------------------------------------------------------------------------
// Persistent LSTM: grid 128 = (b, he), 1 blk/CU, wave-autonomous, tagged
// agent-scope h words (bf16<<16 | r+1), parity ping-pong — the R11-proven
// software-pipelined schedule, plus SPLIT GEMM_X: the second half (ks4-7,
// ~300cy of MFMA) runs between G1's issue and G1's consume, shrinking G1's
// exposed round-trip. Everything else identical to the 237us R11 kernel.
// ---------------------------------------------------------------------------
__global__ __launch_bounds__(256, 1) void lstm_kernel(
        const unsigned int* __restrict__ xT32,
        const unsigned short* __restrict__ Wx,
        const unsigned short* __restrict__ Wh,
        const float* __restrict__ bias_p,
        unsigned int* ht,
        float* __restrict__ out) {
    __shared__ __align__(16) unsigned short lds_bx[WXSZ];           // 32 KiB
    __shared__ __align__(16) unsigned short lds_bh[WHSZ];           // 48 KiB
    __shared__ __align__(16) unsigned short ldsx[4][2][17 * LROW];  // 36.1 KiB
    __shared__ __align__(16) unsigned short ldsh[4][18 * LROW];     // 19.1 KiB

    const int tid  = threadIdx.x;
    const int b    = blockIdx.x & 15;
    const int he   = blockIdx.x >> 4;
    const int wv   = tid >> 6;
    const int lane = tid & 63;
    const int quad = lane >> 4;
    const int l15  = lane & 15;

    // ---- prologue: weight slices -> LDS (block-coop, once) ----
    {
        const u32x4* src = (const u32x4*)(Wx + (size_t)he * WXSZ);
        u32x4* dst = (u32x4*)lds_bx;
#pragma unroll
        for (int p = 0; p < 8; ++p) dst[p * 256 + tid] = src[p * 256 + tid];
        const u32x4* srh = (const u32x4*)(Wh + (size_t)he * WHSZ);
        u32x4* dsh = (u32x4*)lds_bh;
#pragma unroll
        for (int p = 0; p < 12; ++p) dsh[p * 256 + tid] = srh[p * 256 + tid];
    }

    // per-lane poll geometry: word i covers (row_i, ch32_i); rows clamped,
    // halo rows masked (tag substituted with `want`, data -> bf16 0)
    int  hoffw[9];      // word offset rc*128 + ch32 (group adds g*32)
    unsigned okm[9];
#pragma unroll
    for (int i = 0; i < 9; ++i) {
        int wi = i * 64 + lane;
        int row_i = wi >> 5, ch32 = wi & 31;
        int rr = wv * 16 - 1 + row_i;
        int rc = rr < 0 ? 0 : (rr > 63 ? 63 : rr);
        hoffw[i] = rc * 128 + ch32;
        okm[i]   = ((unsigned)rr < 64u) ? 0xffffffffu : 0u;
    }

#define HPTRS(PP, HS, GRP)                                                     \
    _Pragma("unroll")                                                          \
    for (int i = 0; i < 9; ++i) (PP)[i] = (HS) + hoffw[i] + (GRP) * 32;

#define HCHECK(HV, WANT, DIFF)                                                 \
    {                                                                          \
        (DIFF) = 0u;                                                           \
        _Pragma("unroll")                                                      \
        for (int i = 0; i < 9; ++i) {                                          \
            (HV)[i] = ((HV)[i] & okm[i]) | ((WANT) & ~okm[i]);                 \
            (DIFF) |= ((HV)[i] ^ (WANT)) & 0xffffu;                            \
        }                                                                      \
    }

#define HSPIN(HV, PP, WANT)                                                    \
    {                                                                          \
        __builtin_amdgcn_s_setprio(0);                                         \
        for (;;) {                                                             \
            ld9_issue((HV), (PP)); wait9((HV));                                \
            unsigned d_; HCHECK((HV), (WANT), d_);                             \
            if (__ballot(d_ != 0u) == 0ull) break;                             \
        }                                                                      \
        __builtin_amdgcn_s_setprio(1);                                         \
    }

#define HSTAGE(HV, GRP, HP)                                                    \
    _Pragma("unroll")                                                          \
    for (int i = 0; i < 9; ++i) {                                              \
        int wi = i * 64 + lane;                                                \
        (HP)[(wi >> 5) * LROW + (GRP) * 32 + (wi & 31)] =                      \
            (unsigned short)((HV)[i] >> 16);                                   \
    }

#define HGEMM(GRP, HP)                                                         \
    _Pragma("unroll")                                                          \
    for (int t = 0; t < 3; ++t) {                                              \
        const int ks = (GRP) * 3 + t;                                          \
        short8 a = *(const short8*)&(HP)[(l15 + t) * LROW + (GRP) * 32 + quad * 8]; \
        _Pragma("unroll")                                                      \
        for (int g = 0; g < 4; ++g) {                                          \
            short8 bq = *(const short8*)&lds_bh[((g * 12 + ks) * 64 + lane) * 8]; \
            acc[g] = __builtin_amdgcn_mfma_f32_16x16x32_bf16(a, bq, acc[g], 0, 0, 0); \
        }                                                                      \
    }

// half of the x-part GEMM: ks = KS0 .. KS0+3
#define GEMM_XH(XP, KS0)                                                       \
    _Pragma("unroll")                                                          \
    for (int ks = (KS0); ks < (KS0) + 4; ++ks) {                               \
        const int t = ks >> 2, c0 = (ks & 3) * 32;                             \
        short8 a = *(const short8*)&(XP)[(l15 + t) * LROW + c0 + quad * 8];    \
        _Pragma("unroll")                                                      \
        for (int g = 0; g < 4; ++g) {                                          \
            short8 bq = *(const short8*)&lds_bx[((g * 8 + ks) * 64 + lane) * 8]; \
            acc[g] = __builtin_amdgcn_mfma_f32_16x16x32_bf16(a, bq, acc[g], 0, 0, 0); \
        }                                                                      \
    }

    // initial x stage (row 0) straight to LDS
    {
        const unsigned* xs = xT32 + ((size_t)(b * 64 + 0) * 64) * 64;
#pragma unroll
        for (int i = 0; i < 17; ++i) {
            int rr = wv * 16 - 1 + i;
            ((unsigned*)ldsx[wv][0])[i * 68 + lane] = (rr >= 0) ? xs[rr * 64 + lane] : 0u;
        }
    }
    __syncthreads();                     // weights + x0 ready (only barrier)
    __builtin_amdgcn_s_setprio(1);

    const int hch = he * 16 + l15;
    const float bi  = bias_p[      hch];
    const float bf_ = bias_p[128 + hch];
    const float bo  = bias_p[256 + hch];
    const float bg  = bias_p[384 + hch];

    f32x4 creg = (f32x4){0.f, 0.f, 0.f, 0.f};

    for (int r = 0; r < HDIM; ++r) {
        const unsigned want = (unsigned)r;
        const unsigned* hs = ht + ((size_t)((r - 1) & 1) * NBATCH + b) * (WDIM * HID);
        unsigned short* hp = ldsh[wv];

        // issue G0 poll loads first (RT hides under x prefetch + GEMM_X half 1)
        unsigned hva[9], hvb[9];
        const unsigned* ppa[9]; const unsigned* ppb[9];
        if (r > 0) { HPTRS(ppa, hs, 0); ld9_issue(hva, ppa); }

        // x prefetch for r+1 into registers (ds_write deferred to row end)
        unsigned xr[17];
        if (r < HDIM - 1) {
            const unsigned* xs = xT32 + ((size_t)(b * 64 + r + 1) * 64) * 64;
#pragma unroll
            for (int i = 0; i < 17; ++i) {
                int rr = wv * 16 - 1 + i;
                xr[i] = (rr >= 0) ? xs[rr * 64 + lane] : 0u;
            }
        }

        f32x4 acc[4];
#pragma unroll
        for (int g = 0; g < 4; ++g) acc[g] = (f32x4){0.f, 0.f, 0.f, 0.f};

        GEMM_XH(ldsx[wv][r & 1], 0);                       // x-part ks 0..3

        unsigned diff;
        if (r > 0) {
            // --- G0: consume (RT spent under xr prefetch + XH1) ---
            wait9(hva); HCHECK(hva, want, diff);
            if (__ballot(diff != 0u) != 0ull) HSPIN(hva, ppa, want);
            HPTRS(ppb, hs, 1); ld9_issue(hvb, ppb);        // issue G1
            HSTAGE(hva, 0, hp); HGEMM(0, hp);
        }

        GEMM_XH(ldsx[wv][r & 1], 4);                       // x-part ks 4..7 (hides G1 RT)

        if (r > 0) {
            // --- G1 ---
            wait9(hvb); HCHECK(hvb, want, diff);
            if (__ballot(diff != 0u) != 0ull) HSPIN(hvb, ppb, want);
            HPTRS(ppa, hs, 2); ld9_issue(hva, ppa);        // issue G2
            HSTAGE(hvb, 1, hp); HGEMM(1, hp);
            // --- G2 ---
            wait9(hva); HCHECK(hva, want, diff);
            if (__ballot(diff != 0u) != 0ull) HSPIN(hva, ppa, want);
            HPTRS(ppb, hs, 3); ld9_issue(hvb, ppb);        // issue G3
            HSTAGE(hva, 2, hp); HGEMM(2, hp);
            // --- G3 ---
            wait9(hvb); HCHECK(hvb, want, diff);
            if (__ballot(diff != 0u) != 0ull) HSPIN(hvb, ppb, want);
            HSTAGE(hvb, 3, hp); HGEMM(3, hp);
        }

        // ---- epilogue: gates lane-local; publish each h word ASAP ----
        {
            const int w0 = wv * 16 + quad * 4;
            unsigned* hb = ht + ((size_t)(r & 1) * NBATCH + b) * (WDIM * HID);
            f32x4 hv;
#pragma unroll
            for (int e = 0; e < 4; ++e) {
                float zi = acc[0][e] + bi;
                float zf = acc[1][e] + bf_;
                float zo = acc[2][e] + bo;
                float zg = acc[3][e] + bg;
                float ig = sigm(zi), fg = sigm(zf), og = sigm(zo);
                float gg = tanhft(zg);
                float cn = fg * creg[e] + ig * gg;
                creg[e] = cn;
                hv[e]   = og * tanhft(cn);
                ASTOREA(&hb[(w0 + e) * 128 + hch],
                        ((unsigned)f2bf(hv[e]) << 16) | (unsigned)(r + 1));
            }
            *(f32x4*)&out[(((size_t)b * HID + hch) * HDIM + r) * WDIM + w0] = hv;
        }

        // deferred x ds_write for row r+1 (off the inter-block critical path)
        if (r < HDIM - 1) {
            unsigned* xp = (unsigned*)ldsx[wv][(r + 1) & 1];
#pragma unroll
            for (int i = 0; i < 17; ++i) xp[i * 68 + lane] = xr[i];
        }
    }
}

extern "C" void kernel_launch(void* const* d_in, const int* in_sizes, int n_in,
                              void* d_out, int out_size, void* d_ws, size_t ws_size,
                              hipStream_t stream) {
    const float* x    = (const float*)d_in[0];
    const float* W_is = (const float*)d_in[1];
    const float* b_is = (const float*)d_in[2];
    const float* W_ss = (const float*)d_in[3];
    const float* b_ss = (const float*)d_in[4];
    float* out = (float*)d_out;

    // ws: xT bf16[16][64][64][128] | ht u32 | Wx | Wh | bias
    const size_t XT_BYTES = (size_t)16 * 64 * 64 * 128 * 2;   // 16777216
    const size_t HT_BYTES = (size_t)HTWORDS * 4;              //  1048576
    const size_t WX_BYTES = 8 * WXSZ * 2;                     //   262144
    const size_t WH_BYTES = 8 * WHSZ * 2;                     //   393216

    unsigned int*   xT32   = (unsigned int*)d_ws;
    unsigned int*   ht     = (unsigned int*)((char*)d_ws + XT_BYTES);
    unsigned short* Wx     = (unsigned short*)((char*)d_ws + XT_BYTES + HT_BYTES);
    unsigned short* Wh     = (unsigned short*)((char*)d_ws + XT_BYTES + HT_BYTES + WX_BYTES);
    float*          bias_p = (float*)((char*)d_ws + XT_BYTES + HT_BYTES + WX_BYTES + WH_BYTES);

    prep_kernel<<<2048, 256, 0, stream>>>(W_is, b_is, W_ss, b_ss, x,
                                          Wx, Wh, bias_p, ht, xT32);
    lstm_kernel<<<128, 256, 0, stream>>>(xT32, Wx, Wh, bias_p, ht, out);
}